// Round 9
// baseline (166.398 us; speedup 1.0000x reference)
//
#include <hip/hip_runtime.h>

// SSIM 3D, round 12 = round 8's verified barrier-free body + DSUB 16->8 for
// 2x grid, enabled by __launch_bounds__(256,2).
// Session model (now twice-confirmed): allocator arch-VGPR budget =
// 512/min_waves_per_EU/2 -> (256,4) pins 64, (256,8) pins 32; live sets over
// the pin spill to scratch (r4/r5/r6/r9/r10: 0.2-1.1 GB WRITE_SIZE), they
// never allocate 65+. (256,2) caps at ~128: r11 took 76 regs, ZERO spill.
// r11 also refuted the prefetch theory (neutral): phase-head load latency is
// covered by TLP; the remaining ~45% VALU idle is the intra-wave serial chain
// (W-conv -> ds_write -> lgkm -> ds_read -> H -> D). Only MORE WAVES cover
// that -> this round buys occupancy work-efficiently:
//   DSUB=8: 2048 blocks; LDS 20.9 KB -> 7 blocks/CU = 28 waves/CU (was 16).
//   +20% W/H/load work (12 slices per 8 outputs vs 20/16); D/SSIM unchanged.
// Spill-safe shapes kept: r8 fence body (no prefetch regs), 5-phase loop
// region x2 + 2-phase tail (r6's straight-line-12 was a spill trigger),
// plain partials tail.
// Tripwires: WRITE_SIZE < 1 MB (spill detector; VGPR_Count lies), VGPR 64-80.
// Tile: W=128 (4 waves x 32 cols), TH=4 rows, DSUB=8 -> 2048 blocks.

#define NDIM 128
#define TH 4
#define WR (TH + 4)            // 8 W-conv rows
#define DSUB 8
#define NHT (NDIM / TH)        // 32
#define NDT (NDIM / DSUB)      // 16
#define NB 4
#define NBLK (NHT * NDT * NB)  // 2048

__global__ void factorize_window(const float* __restrict__ w, float* __restrict__ ws) {
    if (threadIdx.x == 0) {
        float w000 = w[0];
        #pragma unroll
        for (int i = 0; i < 5; ++i) ws[i]      = w[i * 25];
        #pragma unroll
        for (int j = 0; j < 5; ++j) ws[5 + j]  = w[j * 5] / w000;
        #pragma unroll
        for (int k = 0; k < 5; ++k) ws[10 + k] = w[k] / w000;
    }
}

__launch_bounds__(256, 2)
__global__ void ssim_main(const float* __restrict__ img1,
                          const float* __restrict__ img2,
                          const float* __restrict__ wfac,
                          float* __restrict__ partials) {
    const int bid = blockIdx.x;
    const int th = bid % NHT;
    const int td = (bid / NHT) % NDT;
    const int b  = bid / (NHT * NDT);

    const int h0 = th * TH, d0 = td * DSUB;
    const float* __restrict__ x1 = img1 + (size_t)(b * 2 + 1) * NDIM * NDIM * NDIM;
    const float* __restrict__ x2 = img2 + (size_t)b * NDIM * NDIM * NDIM;

    float uW[5], vW[5], tW[5];
    #pragma unroll
    for (int i = 0; i < 5; ++i) { uW[i] = wfac[i]; vW[i] = wfac[5 + i]; tW[i] = wfac[10 + i]; }

    __shared__ float sWc[5][WR][NDIM];   // 20 KB; wave w uses cols [32w,32w+32)
    __shared__ float sRed[4];

    const int tid  = threadIdx.x;
    const int wv   = tid >> 6;           // wave id 0..3 -> col stripe
    const int lane = tid & 63;
    const int sc   = wv * 32;            // stripe col base
    // W-conv mapping (per wave): 8 rows x 8 col-groups of 4
    const int wrow = lane >> 3;          // 0..7
    const int wg   = lane & 7;           // 0..7
    const int c0   = sc + wg * 4;        // global col of this lane's 4 outputs
    const int ghw  = h0 + wrow - 2;
    // H/D mapping (per wave): 4 rows x 16 col-pairs of 2
    const int orow = lane >> 4;          // 0..3
    const int oc   = sc + (lane & 15) * 2;

    float2 ring[5][5];                   // [slot][field], static indices only
    float2 accS = make_float2(0.f, 0.f);

#define PHASE(I, P) do {                                                       \
    const int i_ = (I);                                                        \
    const int d_ = d0 - 2 + i_;                                                \
    float4 A0 = make_float4(0,0,0,0), A1 = A0, A2 = A0;                        \
    float4 B0 = A0, B1 = A0, B2 = A0;                                          \
    if (((unsigned)d_ < NDIM) && ((unsigned)ghw < NDIM)) {                     \
        const float* __restrict__ r1_ = x1 + ((size_t)d_ * NDIM + ghw) * NDIM; \
        const float* __restrict__ r2_ = x2 + ((size_t)d_ * NDIM + ghw) * NDIM; \
        if (c0 > 0)   { A0 = *(const float4*)(r1_ + c0 - 4);                   \
                        B0 = *(const float4*)(r2_ + c0 - 4); }                 \
        A1 = *(const float4*)(r1_ + c0);                                       \
        B1 = *(const float4*)(r2_ + c0);                                       \
        if (c0 < 124) { A2 = *(const float4*)(r1_ + c0 + 4);                   \
                        B2 = *(const float4*)(r2_ + c0 + 4); }                 \
    }                                                                          \
    float ra[12] = {A0.x,A0.y,A0.z,A0.w, A1.x,A1.y,A1.z,A1.w,                  \
                    A2.x,A2.y,A2.z,A2.w};                                      \
    float rb[12] = {B0.x,B0.y,B0.z,B0.w, B1.x,B1.y,B1.z,B1.w,                  \
                    B2.x,B2.y,B2.z,B2.w};                                      \
    float m1v[4], m2v[4], q11v[4], q22v[4], q12v[4];                           \
    _Pragma("unroll")                                                          \
    for (int k_ = 0; k_ < 4; ++k_) {                                           \
        float m1_=0.f, m2_=0.f, q11_=0.f, q22_=0.f, q12_=0.f;                  \
        _Pragma("unroll")                                                      \
        for (int c_ = 0; c_ < 5; ++c_) {                                       \
            const float a_ = ra[k_ + c_ + 2], b_ = rb[k_ + c_ + 2];            \
            const float ta_ = tW[c_] * a_, tb_ = tW[c_] * b_;                  \
            m1_ += ta_; m2_ += tb_;                                            \
            q11_ += ta_ * a_; q22_ += tb_ * b_; q12_ += ta_ * b_;              \
        }                                                                      \
        m1v[k_]=m1_; m2v[k_]=m2_; q11v[k_]=q11_; q22v[k_]=q22_; q12v[k_]=q12_; \
    }                                                                          \
    /* fence: prior phase's intra-wave LDS reads ordered before these writes;  \
       HW processes a wave's DS ops in issue order. Also the scheduling fence  \
       that prevents cross-phase load-hoist spills (r4-r6 lesson). */          \
    asm volatile("" ::: "memory");                                             \
    *(float4*)&sWc[0][wrow][c0] = make_float4(m1v[0],m1v[1],m1v[2],m1v[3]);    \
    *(float4*)&sWc[1][wrow][c0] = make_float4(m2v[0],m2v[1],m2v[2],m2v[3]);    \
    *(float4*)&sWc[2][wrow][c0] = make_float4(q11v[0],q11v[1],q11v[2],q11v[3]);\
    *(float4*)&sWc[3][wrow][c0] = make_float4(q22v[0],q22v[1],q22v[2],q22v[3]);\
    *(float4*)&sWc[4][wrow][c0] = make_float4(q12v[0],q12v[1],q12v[2],q12v[3]);\
    asm volatile("" ::: "memory");  /* writes ordered before the reads below */\
    _Pragma("unroll")                                                          \
    for (int f_ = 0; f_ < 5; ++f_) {                                           \
        float2 F_ = make_float2(0.f, 0.f);                                     \
        _Pragma("unroll")                                                      \
        for (int r_ = 0; r_ < 5; ++r_) {                                       \
            const float2 wv_ = *(const float2*)&sWc[f_][orow + r_][oc];        \
            F_.x += vW[r_] * wv_.x;                                            \
            F_.y += vW[r_] * wv_.y;                                            \
        }                                                                      \
        ring[(P)][f_] = F_;                                                    \
    }                                                                          \
    if (i_ >= 4) {                                                             \
        float2 F0 = make_float2(0,0), F1 = F0, F2 = F0, F3 = F0, F4 = F0;      \
        _Pragma("unroll")                                                      \
        for (int j_ = 0; j_ < 5; ++j_) {                                       \
            const int s_ = ((P) + 1 + j_) % 5;                                 \
            const float uw_ = uW[j_];                                          \
            F0.x += uw_*ring[s_][0].x; F0.y += uw_*ring[s_][0].y;              \
            F1.x += uw_*ring[s_][1].x; F1.y += uw_*ring[s_][1].y;              \
            F2.x += uw_*ring[s_][2].x; F2.y += uw_*ring[s_][2].y;              \
            F3.x += uw_*ring[s_][3].x; F3.y += uw_*ring[s_][3].y;              \
            F4.x += uw_*ring[s_][4].x; F4.y += uw_*ring[s_][4].y;              \
        }                                                                      \
        {                                                                      \
            const float mu1 = F0.x, mu2 = F1.x;                                \
            const float m11 = mu1*mu1, m22 = mu2*mu2, m12 = mu1*mu2;           \
            const float num = (2.f*m12 + 1e-4f) * (2.f*(F4.x - m12) + 9e-4f);  \
            const float den = (m11 + m22 + 1e-4f) *                            \
                              ((F2.x - m11) + (F3.x - m22) + 9e-4f);           \
            accS.x += __fdividef(num, den);                                    \
        }                                                                      \
        {                                                                      \
            const float mu1 = F0.y, mu2 = F1.y;                                \
            const float m11 = mu1*mu1, m22 = mu2*mu2, m12 = mu1*mu2;           \
            const float num = (2.f*m12 + 1e-4f) * (2.f*(F4.y - m12) + 9e-4f);  \
            const float den = (m11 + m22 + 1e-4f) *                            \
                              ((F2.y - m11) + (F3.y - m22) + 9e-4f);           \
            accS.y += __fdividef(num, den);                                    \
        }                                                                      \
    }                                                                          \
} while (0)

    // 12 slices: d0-2 .. d0+9. Proven 5-phase loop region x2 + 2-phase tail
    // (r6's straight-line 12-phase region was a spill trigger; avoid).
    for (int io = 0; io < 2; ++io) {
        const int ib = io * 5;
        PHASE(ib + 0, 0);
        PHASE(ib + 1, 1);
        PHASE(ib + 2, 2);
        PHASE(ib + 3, 3);
        PHASE(ib + 4, 4);
    }
    PHASE(10, 0);
    PHASE(11, 1);
#undef PHASE

    float acc = accS.x + accS.y;
    #pragma unroll
    for (int off = 32; off > 0; off >>= 1)
        acc += __shfl_down(acc, off, 64);
    __syncthreads();                     // only cross-wave sync in the kernel
    if (lane == 0) sRed[wv] = acc;
    __syncthreads();
    if (tid == 0) partials[bid] = sRed[0] + sRed[1] + sRed[2] + sRed[3];
}

__global__ void finalize_kernel(const float* __restrict__ partials, float* __restrict__ out) {
    const int tid = threadIdx.x;
    double s = 0.0;
    for (int i = tid; i < NBLK; i += 256) s += (double)partials[i];
    #pragma unroll
    for (int off = 32; off > 0; off >>= 1)
        s += __shfl_down(s, off, 64);
    __shared__ double sm[4];
    if ((tid & 63) == 0) sm[tid >> 6] = s;
    __syncthreads();
    if (tid == 0)
        out[0] = 1.0f - (float)((sm[0] + sm[1] + sm[2] + sm[3]) / (double)(4LL * 128 * 128 * 128));
}

extern "C" void kernel_launch(void* const* d_in, const int* in_sizes, int n_in,
                              void* d_out, int out_size, void* d_ws, size_t ws_size,
                              hipStream_t stream) {
    const float* img1 = (const float*)d_in[0];   // (4,2,128,128,128) fp32
    const float* img2 = (const float*)d_in[1];   // (4,1,128,128,128) fp32
    const float* win  = (const float*)d_in[2];   // (1,1,5,5,5) fp32
    float* out = (float*)d_out;
    float* ws  = (float*)d_ws;
    float* wfac     = ws;         // 16 floats
    float* partials = ws + 16;    // NBLK floats, fully rewritten every launch

    hipLaunchKernelGGL(factorize_window, dim3(1), dim3(64), 0, stream, win, wfac);
    hipLaunchKernelGGL(ssim_main, dim3(NBLK), dim3(256), 0, stream, img1, img2, wfac, partials);
    hipLaunchKernelGGL(finalize_kernel, dim3(1), dim3(256), 0, stream, partials, out);
}